// Round 22
// baseline (107.312 us; speedup 1.0000x reference)
//
#include <hip/hip_runtime.h>

// WindowAttention fused, MI355X gfx950 — R21: R20 (101us best) + softmax
// bias+mask PRE-COMBINED into one bf16 LDS table during the stage phase
// (latency hides under x-load wait). Softmax reads 1 ushort4/LDS per (qt,kt);
// its 16 global bias float4s + 16 LDS mask float4s are gone from the chain.
// B=4096 windows, N=49 (pad 64), C=128, H=4 heads, d=32. wave w = head w.

typedef short bf16x4 __attribute__((ext_vector_type(4)));
typedef short bf16x8 __attribute__((ext_vector_type(8)));
typedef float f32x4 __attribute__((ext_vector_type(4)));
typedef unsigned int u32x4 __attribute__((ext_vector_type(4)));

#define MFMA_K32(a, b, c) __builtin_amdgcn_mfma_f32_16x16x32_bf16((a), (b), (c), 0, 0, 0)
#define MFMA_K16(a, b, c) __builtin_amdgcn_mfma_f32_16x16x16bf16_1k((a), (b), (c), 0, 0, 0)

// pack two fp32 -> two bf16 (round-half-up) in one u32 (R1-verified)
__device__ __forceinline__ unsigned pk2(float lo, float hi) {
  return __builtin_amdgcn_perm(__float_as_uint(hi) + 0x8000u,
                               __float_as_uint(lo) + 0x8000u, 0x07060302u);
}
__device__ __forceinline__ unsigned short bf1(float v) {
  return (unsigned short)((__float_as_uint(v) + 0x8000u) >> 16);
}
__device__ __forceinline__ float b2f(unsigned short u) {
  return __uint_as_float(((unsigned)u) << 16);
}
__device__ __forceinline__ bf16x4 pack4(float a, float b, float c, float d) {
  union { unsigned u[2]; bf16x4 h; } r;
  r.u[0] = pk2(a, b); r.u[1] = pk2(c, d);
  return r.h;
}

// ---- workspace layout (bytes) ----
// qkvP : bf16 [16 kc][384 n][8 k]  (k-chunk-major; q-scale folded into n<128)
// projP: bf16 [16 kc][128 n][8 k]
// bsc  : f32  [384] qkv_b (q part scaled)
// Bh   : bf16 [4 h][13 k4][49 q][4 ki]  rel-pos bias in combined layout
#define OFF_QKVT  0u
#define OFF_PROJT 98304u
#define OFF_BSC   131072u
#define OFF_BH    132608u

__global__ void prep_kernel(const float* __restrict__ qkv_w,
                            const float* __restrict__ qkv_b,
                            const float* __restrict__ proj_w,
                            const float* __restrict__ bias_table,
                            const int*   __restrict__ rel_index,
                            char* __restrict__ ws) {
  const float scale = 0.17677669529663687f;  // 32^-0.5
  int idx = blockIdx.x * 256 + threadIdx.x;
  if (idx < 49152) {                 // qkvP[((k>>3)*384 + n)*8 + (k&7)] = w[k][n]
    int n = idx >> 7, k = idx & 127;
    float v = qkv_w[k * 384 + n];
    if (n < 128) v *= scale;
    ((unsigned short*)(ws + OFF_QKVT))[(((k >> 3) * 384) + n) * 8 + (k & 7)] = bf1(v);
  } else if (idx < 65536) {          // projP[((k>>3)*128 + n)*8 + (k&7)] = w[k][n]
    int j = idx - 49152;
    int n = j >> 7, k = j & 127;
    ((unsigned short*)(ws + OFF_PROJT))[(((k >> 3) * 128) + n) * 8 + (k & 7)] = bf1(proj_w[k * 128 + n]);
  } else if (idx < 65920) {          // scaled qkv bias
    int j = idx - 65536;
    if (j < 384) {
      float v = qkv_b[j];
      if (j < 128) v *= scale;
      ((float*)(ws + OFF_BSC))[j] = v;
    }
  } else if (idx < 76112) {          // Bh[h][k4][q][ki] bf16
    int j = idx - 65920;
    int h = j / 2548, r = j - h * 2548;
    int k4 = r / 196, r2 = r - k4 * 196;
    int q = r2 >> 2, ki = r2 & 3;
    int key = 4 * k4 + ki;
    float v = (key < 49) ? bias_table[rel_index[q * 49 + key] * 4 + h] : 0.f;
    ((unsigned short*)(ws + OFF_BH))[j] = bf1(v);
  }
}

// LDS: [0,32768)       xs fp32 [64 tok][512B row], byte = tok*512 + (col ^ ((tok&15)<<5))
//                      Rows 49..63 zeroed. First 16KB reused as `mid` bf16
//                      [64][256B] (byte = tok*256 + (2d ^ ((tok&15)<<4))).
//      [32768,53152)   cmb bf16 [4 h][13 k4][49 q][4 ki] = bf16(mask + bias);
//                      byte = CMB + h*5096 + k4*392 + q*8 + ki*2.
//                      (k4,q clamped at read; garbage rows killed by selects)
#define CMB 32768u

__global__ __launch_bounds__(256, 3)
void win_attn_kernel(const float* __restrict__ x,
                     const float* __restrict__ mask,
                     const float* __restrict__ proj_b,
                     const char*  __restrict__ ws,
                     float* __restrict__ out) {
  __shared__ __align__(16) char smem[53152];
  const int b    = blockIdx.x;
  const int tid  = threadIdx.x;
  const int w    = tid >> 6;        // wave id == head id
  const int lane = tid & 63;
  const int l16  = lane & 15;
  const int lg   = lane >> 4;

  const unsigned short* qkvP  = (const unsigned short*)(ws + OFF_QKVT);
  const unsigned short* projP = (const unsigned short*)(ws + OFF_PROJT);
  const float* bsc = (const float*)(ws + OFF_BSC);
  const unsigned short* BhP = (const unsigned short*)(ws + OFF_BH);

  // ======== stage x (fp32, 512+XOR) + combined (mask+bias -> bf16) -> LDS ========
  {
    const float* xb = x + (size_t)b * 6272;
#pragma unroll
    for (int it = 0; it < 8; ++it) {
      int idx = tid + it * 256;                // 2048 chunks of 16B: tok*32+c
      int tok = idx >> 5, c = idx & 31;
      unsigned off = (unsigned)tok * 512u +
                     (((unsigned)c * 16u) ^ (((unsigned)tok & 15u) << 5));
      if (tok < 49) {
        *(float4*)(smem + off) = *(const float4*)(xb + tok * 128 + c * 4);
      } else {
        *(float4*)(smem + off) = make_float4(0.f, 0.f, 0.f, 0.f);
      }
    }
    const float* mb = mask + (size_t)b * 2401;
#pragma unroll
    for (int it = 0; it < 40; ++it) {
      int j = tid + it * 256;                  // [h][k4][q][ki], 10192 entries
      if (j < 10192) {
        int h = j / 2548, r = j - h * 2548;
        int k4 = r / 196, r2 = r - k4 * 196;
        int q = r2 >> 2, ki = r2 & 3;
        int key = 4 * k4 + ki;
        int keyc = key > 48 ? 48 : key;
        float m = mb[q * 49 + keyc];
        float v = m + b2f(BhP[j]);
        *(unsigned short*)(smem + CMB + (unsigned)j * 2u) = bf1(v);
      }
    }
  }
  __syncthreads();

  // x fragment from LDS (lane = token l16), pack fp32->bf16 at read (R12 pattern)
  auto xfrag = [&](int tt, int ks) -> bf16x8 {
    int tok = 16 * tt + l16;
    unsigned col = (unsigned)(128 * ks + 32 * lg);
    unsigned off = (unsigned)tok * 512u + (col ^ (((unsigned)tok & 15u) << 5));
    float4 v0 = *(const float4*)(smem + off);
    float4 v1 = *(const float4*)(smem + off + 16);
    union { u32x4 u; bf16x8 h; } pk;
    pk.u.x = pk2(v0.x, v0.y); pk.u.y = pk2(v0.z, v0.w);
    pk.u.z = pk2(v1.x, v1.y); pk.u.w = pk2(v1.z, v1.w);
    return pk.h;
  };

  // coalesced W fragment: k-chunk kc = 4ks+lg, rows n..n+15 consecutive
  auto wfrag = [&](const unsigned short* base, int N, int kc, int n) -> bf16x8 {
    return *(const bf16x8*)(base + ((size_t)kc * N + n) * 8);
  };

  // ============ GEMM1 pass A: Q^T,K^T tiles = mfma(W^T-frag, x-frag) ============
  f32x4 qt_acc[2][4], kt_acc[2][4];
#pragma unroll
  for (int dt = 0; dt < 2; ++dt) {
    f32x4 qb, kb;
#pragma unroll
    for (int i = 0; i < 4; ++i) {
      qb[i] = bsc[32 * w + 16 * dt + 4 * lg + i];
      kb[i] = bsc[128 + 32 * w + 16 * dt + 4 * lg + i];
    }
#pragma unroll
    for (int tt = 0; tt < 4; ++tt) { qt_acc[dt][tt] = qb; kt_acc[dt][tt] = kb; }
  }
#pragma unroll
  for (int ks = 0; ks < 4; ++ks) {
    int kc = 4 * ks + lg;
    bf16x8 xf[4];
#pragma unroll
    for (int tt = 0; tt < 4; ++tt) xf[tt] = xfrag(tt, ks);
#pragma unroll
    for (int dt = 0; dt < 2; ++dt) {
      bf16x8 wq = wfrag(qkvP, 384, kc, 32 * w + 16 * dt + l16);
      bf16x8 wk = wfrag(qkvP, 384, kc, 128 + 32 * w + 16 * dt + l16);
#pragma unroll
      for (int tt = 0; tt < 4; ++tt) {
        qt_acc[dt][tt] = MFMA_K32(wq, xf[tt], qt_acc[dt][tt]);
        kt_acc[dt][tt] = MFMA_K32(wk, xf[tt], kt_acc[dt][tt]);
      }
    }
  }
  bf16x4 qf[4][2], kf[4][2];
#pragma unroll
  for (int tt = 0; tt < 4; ++tt)
#pragma unroll
    for (int dt = 0; dt < 2; ++dt) {
      qf[tt][dt] = pack4(qt_acc[dt][tt][0], qt_acc[dt][tt][1], qt_acc[dt][tt][2], qt_acc[dt][tt][3]);
      kf[tt][dt] = pack4(kt_acc[dt][tt][0], kt_acc[dt][tt][1], kt_acc[dt][tt][2], kt_acc[dt][tt][3]);
    }

  // ============ GEMM1 pass B: V tiles = mfma(x-frag, Wv^T-frag) ============
  f32x4 v_acc[4][2];
  {
    float vb0 = bsc[256 + 32 * w + l16];
    float vb1 = bsc[256 + 32 * w + 16 + l16];
#pragma unroll
    for (int tt = 0; tt < 4; ++tt) {
      v_acc[tt][0] = (f32x4){vb0, vb0, vb0, vb0};
      v_acc[tt][1] = (f32x4){vb1, vb1, vb1, vb1};
    }
  }
#pragma unroll
  for (int ks = 0; ks < 4; ++ks) {
    int kc = 4 * ks + lg;
    bf16x8 xf[4];
#pragma unroll
    for (int tt = 0; tt < 4; ++tt) xf[tt] = xfrag(tt, ks);   // LDS re-read, cheap
#pragma unroll
    for (int dt = 0; dt < 2; ++dt) {
      bf16x8 wv = wfrag(qkvP, 384, kc, 256 + 32 * w + 16 * dt + l16);
#pragma unroll
      for (int tt = 0; tt < 4; ++tt) v_acc[tt][dt] = MFMA_K32(xf[tt], wv, v_acc[tt][dt]);
    }
  }
  bf16x4 vf[2][4];
#pragma unroll
  for (int dt = 0; dt < 2; ++dt)
#pragma unroll
    for (int tt = 0; tt < 4; ++tt)
      vf[dt][tt] = pack4(v_acc[tt][dt][0], v_acc[tt][dt][1], v_acc[tt][dt][2], v_acc[tt][dt][3]);

  __syncthreads();   // all waves done reading xs; first 16KB becomes `mid`

  // ============ QK^T (K=16): S^T[key][q] tiles, lane = q, regs = key ============
  f32x4 s_acc[4][4];  // [kt][qt]
#pragma unroll
  for (int kt = 0; kt < 4; ++kt)
#pragma unroll
    for (int qt = 0; qt < 4; ++qt) s_acc[kt][qt] = (f32x4){0.f, 0.f, 0.f, 0.f};
#pragma unroll
  for (int kt = 0; kt < 4; ++kt)
#pragma unroll
    for (int qt = 0; qt < 4; ++qt) {
      s_acc[kt][qt] = MFMA_K16(kf[kt][0], qf[qt][0], s_acc[kt][qt]);
      s_acc[kt][qt] = MFMA_K16(kf[kt][1], qf[qt][1], s_acc[kt][qt]);
    }

  // ====== combined bias+mask: one ushort4 LDS read per (qt,kt) + no-max softmax ======
  const unsigned cmb_base = CMB + (unsigned)w * 5096u;
  float rs_[4];
#pragma unroll
  for (int qt = 0; qt < 4; ++qt) {
    int q = 16 * qt + l16;
    bool qok = q < 49;
    unsigned qoff = (unsigned)(q > 48 ? 48 : q) * 8u;
    float sum = 0.f;
#pragma unroll
    for (int kt = 0; kt < 4; ++kt) {
      int k4 = 4 * kt + lg;
      unsigned k4off = (unsigned)(k4 > 12 ? 12 : k4) * 392u;
      ushort4 mu = *(const ushort4*)(smem + cmb_base + k4off + qoff);
      float ba[4] = {b2f(mu.x), b2f(mu.y), b2f(mu.z), b2f(mu.w)};
#pragma unroll
      for (int i = 0; i < 4; ++i) {
        int key = 16 * kt + 4 * lg + i;
        float v = s_acc[kt][qt][i];
        v = (qok && key < 49) ? (v + ba[i]) : -30000.0f;
        float e = __expf(v - 8.0f);
        s_acc[kt][qt][i] = e;
        sum += e;
      }
    }
    sum += __shfl_xor(sum, 16);
    sum += __shfl_xor(sum, 32);
    rs_[qt] = 1.0f / (sum + 1e-30f);   // padded rows: sum==0 -> rs finite
  }

  // ============ P frags in-register; PV (K=16): O^T[d][q], lane = q ============
  bf16x4 pf[4][4];  // [qt][kt]
#pragma unroll
  for (int qt = 0; qt < 4; ++qt)
#pragma unroll
    for (int kt = 0; kt < 4; ++kt)
      pf[qt][kt] = pack4(s_acc[kt][qt][0], s_acc[kt][qt][1], s_acc[kt][qt][2], s_acc[kt][qt][3]);

  f32x4 o_acc[2][4];  // [dt][qt]: lane = q, regs = d = 4lg+i
#pragma unroll
  for (int dt = 0; dt < 2; ++dt)
#pragma unroll
    for (int qt = 0; qt < 4; ++qt) o_acc[dt][qt] = (f32x4){0.f, 0.f, 0.f, 0.f};
#pragma unroll
  for (int kt = 0; kt < 4; ++kt)
#pragma unroll
    for (int dt = 0; dt < 2; ++dt)
#pragma unroll
      for (int qt = 0; qt < 4; ++qt)
        o_acc[dt][qt] = MFMA_K16(vf[dt][kt], pf[qt][kt], o_acc[dt][qt]);

  // ============ normalize + write mid[q][32w+16dt+4lg..+3] (uint2) ============
#pragma unroll
  for (int qt = 0; qt < 4; ++qt) {
    int q = 16 * qt + l16;
    float r = rs_[qt];
    unsigned rowb = (unsigned)q * 256u, sw = ((unsigned)q & 15u) << 4;
#pragma unroll
    for (int dt = 0; dt < 2; ++dt) {
      unsigned u0 = pk2(o_acc[dt][qt][0] * r, o_acc[dt][qt][1] * r);
      unsigned u1 = pk2(o_acc[dt][qt][2] * r, o_acc[dt][qt][3] * r);
      unsigned L = (unsigned)(64 * w + 32 * dt + 8 * lg);
      *(uint2*)(smem + rowb + (L ^ sw)) = make_uint2(u0, u1);
    }
  }
  __syncthreads();

  // ============ GEMM2 (K=32): out = mid @ projW + b; wave w: cols 32w..32w+31 ============
  f32x4 c2[2][4];
#pragma unroll
  for (int nt = 0; nt < 2; ++nt) {
    float pbv = proj_b[32 * w + 16 * nt + l16];
#pragma unroll
    for (int mt = 0; mt < 4; ++mt) c2[nt][mt] = (f32x4){pbv, pbv, pbv, pbv};
  }
#pragma unroll
  for (int ks = 0; ks < 4; ++ks) {
    int kc = 4 * ks + lg;
    bf16x8 a2[4];
#pragma unroll
    for (int mt = 0; mt < 4; ++mt) {
      int tok = 16 * mt + l16;
      unsigned byte = (unsigned)tok * 256u +
                      (((unsigned)(64 * ks + 16 * lg)) ^ (((unsigned)tok & 15u) << 4));
      a2[mt] = *(const bf16x8*)(smem + byte);
    }
#pragma unroll
    for (int nt = 0; nt < 2; ++nt) {
      bf16x8 b2 = wfrag(projP, 128, kc, 32 * w + 16 * nt + l16);
#pragma unroll
      for (int mt = 0; mt < 4; ++mt) c2[nt][mt] = MFMA_K32(a2[mt], b2, c2[nt][mt]);
    }
  }
  float* ob = out + (size_t)b * 6272;
#pragma unroll
  for (int mt = 0; mt < 4; ++mt)
#pragma unroll
    for (int nt = 0; nt < 2; ++nt)
#pragma unroll
      for (int i = 0; i < 4; ++i) {
        int r = 16 * mt + 4 * lg + i;
        if (r < 49) ob[r * 128 + 32 * w + 16 * nt + l16] = c2[nt][mt][i];
      }
}

extern "C" void kernel_launch(void* const* d_in, const int* in_sizes, int n_in,
                              void* d_out, int out_size, void* d_ws, size_t ws_size,
                              hipStream_t stream) {
  const float* x          = (const float*)d_in[0];
  const float* mask       = (const float*)d_in[1];
  const float* qkv_w      = (const float*)d_in[2];
  const float* qkv_b      = (const float*)d_in[3];
  const float* proj_w     = (const float*)d_in[4];
  const float* proj_b     = (const float*)d_in[5];
  const float* bias_table = (const float*)d_in[6];
  const int*   rel_index  = (const int*)d_in[7];
  char* ws = (char*)d_ws;

  prep_kernel<<<298, 256, 0, stream>>>(qkv_w, qkv_b, proj_w, bias_table, rel_index, ws);
  win_attn_kernel<<<4096, 256, 0, stream>>>(x, mask, proj_b, ws, (float*)d_out);
}

// Round 23
// 99.792 us; speedup vs baseline: 1.0754x; 1.0754x over previous
//
#include <hip/hip_runtime.h>

// WindowAttention fused, MI355X gfx950 — R22: R21's combined bias+mask LDS
// table, but staged with R20-cost addressing: Bh2 pre-laid as [q][key][4h]
// so the stage loop is 10 iters x (1 div + coalesced loads + 4 b16 writes).
// Softmax keeps the single ushort4 read per (qt,kt).
// B=4096 windows, N=49 (pad 64), C=128, H=4 heads, d=32. wave w = head w.

typedef short bf16x4 __attribute__((ext_vector_type(4)));
typedef short bf16x8 __attribute__((ext_vector_type(8)));
typedef float f32x4 __attribute__((ext_vector_type(4)));
typedef unsigned int u32x4 __attribute__((ext_vector_type(4)));

#define MFMA_K32(a, b, c) __builtin_amdgcn_mfma_f32_16x16x32_bf16((a), (b), (c), 0, 0, 0)
#define MFMA_K16(a, b, c) __builtin_amdgcn_mfma_f32_16x16x16bf16_1k((a), (b), (c), 0, 0, 0)

// pack two fp32 -> two bf16 (round-half-up) in one u32 (R1-verified)
__device__ __forceinline__ unsigned pk2(float lo, float hi) {
  return __builtin_amdgcn_perm(__float_as_uint(hi) + 0x8000u,
                               __float_as_uint(lo) + 0x8000u, 0x07060302u);
}
__device__ __forceinline__ unsigned short bf1(float v) {
  return (unsigned short)((__float_as_uint(v) + 0x8000u) >> 16);
}
__device__ __forceinline__ float b2f(unsigned short u) {
  return __uint_as_float(((unsigned)u) << 16);
}
__device__ __forceinline__ bf16x4 pack4(float a, float b, float c, float d) {
  union { unsigned u[2]; bf16x4 h; } r;
  r.u[0] = pk2(a, b); r.u[1] = pk2(c, d);
  return r.h;
}

// ---- workspace layout (bytes) ----
// qkvP : bf16 [16 kc][384 n][8 k]  (k-chunk-major; q-scale folded into n<128)
// projP: bf16 [16 kc][128 n][8 k]
// bsc  : f32  [384] qkv_b (q part scaled)
// Bh2  : bf16 [49 q][49 key][4 h]  rel-pos bias, head-contiguous
#define OFF_QKVT  0u
#define OFF_PROJT 98304u
#define OFF_BSC   131072u
#define OFF_BH    132608u

__global__ void prep_kernel(const float* __restrict__ qkv_w,
                            const float* __restrict__ qkv_b,
                            const float* __restrict__ proj_w,
                            const float* __restrict__ bias_table,
                            const int*   __restrict__ rel_index,
                            char* __restrict__ ws) {
  const float scale = 0.17677669529663687f;  // 32^-0.5
  int idx = blockIdx.x * 256 + threadIdx.x;
  if (idx < 49152) {                 // qkvP[((k>>3)*384 + n)*8 + (k&7)] = w[k][n]
    int n = idx >> 7, k = idx & 127;
    float v = qkv_w[k * 384 + n];
    if (n < 128) v *= scale;
    ((unsigned short*)(ws + OFF_QKVT))[(((k >> 3) * 384) + n) * 8 + (k & 7)] = bf1(v);
  } else if (idx < 65536) {          // projP[((k>>3)*128 + n)*8 + (k&7)] = w[k][n]
    int j = idx - 49152;
    int n = j >> 7, k = j & 127;
    ((unsigned short*)(ws + OFF_PROJT))[(((k >> 3) * 128) + n) * 8 + (k & 7)] = bf1(proj_w[k * 128 + n]);
  } else if (idx < 65920) {          // scaled qkv bias
    int j = idx - 65536;
    if (j < 384) {
      float v = qkv_b[j];
      if (j < 128) v *= scale;
      ((float*)(ws + OFF_BSC))[j] = v;
    }
  } else if (idx < 75524) {          // Bh2[q][key][h] bf16, j = (q*49+key)*4+h
    int j = idx - 65920;
    int qk = j >> 2, h = j & 3;
    int q = qk / 49, key = qk - q * 49;
    ((unsigned short*)(ws + OFF_BH))[j] =
        bf1(bias_table[rel_index[q * 49 + key] * 4 + h]);
  }
}

// LDS: [0,32768)       xs fp32 [64 tok][512B row], byte = tok*512 + (col ^ ((tok&15)<<5))
//                      Rows 49..63 zeroed. First 16KB reused as `mid` bf16
//                      [64][256B] (byte = tok*256 + (2d ^ ((tok&15)<<4))).
//      [32768,53152)   cmb bf16 [4 h][13 k4][49 q][4 ki] = bf16(mask + bias);
//                      byte = CMB + h*5096 + k4*392 + q*8 + ki*2.
//                      (k4,q clamped at read; garbage slots killed by selects)
#define CMB 32768u

__global__ __launch_bounds__(256, 3)
void win_attn_kernel(const float* __restrict__ x,
                     const float* __restrict__ mask,
                     const float* __restrict__ proj_b,
                     const char*  __restrict__ ws,
                     float* __restrict__ out) {
  __shared__ __align__(16) char smem[53152];
  const int b    = blockIdx.x;
  const int tid  = threadIdx.x;
  const int w    = tid >> 6;        // wave id == head id
  const int lane = tid & 63;
  const int l16  = lane & 15;
  const int lg   = lane >> 4;

  const unsigned short* qkvP  = (const unsigned short*)(ws + OFF_QKVT);
  const unsigned short* projP = (const unsigned short*)(ws + OFF_PROJT);
  const float* bsc = (const float*)(ws + OFF_BSC);
  const unsigned short* Bh2 = (const unsigned short*)(ws + OFF_BH);

  // ======== stage x (fp32, 512+XOR) + combined (mask+bias -> bf16) -> LDS ========
  {
    const float* xb = x + (size_t)b * 6272;
#pragma unroll
    for (int it = 0; it < 8; ++it) {
      int idx = tid + it * 256;                // 2048 chunks of 16B: tok*32+c
      int tok = idx >> 5, c = idx & 31;
      unsigned off = (unsigned)tok * 512u +
                     (((unsigned)c * 16u) ^ (((unsigned)tok & 15u) << 5));
      if (tok < 49) {
        *(float4*)(smem + off) = *(const float4*)(xb + tok * 128 + c * 4);
      } else {
        *(float4*)(smem + off) = make_float4(0.f, 0.f, 0.f, 0.f);
      }
    }
    const float* mb = mask + (size_t)b * 2401;
#pragma unroll
    for (int it = 0; it < 10; ++it) {
      int i = tid + it * 256;
      if (i < 2401) {
        int q = i / 49, key = i - q * 49;
        float m = mb[i];
        ushort4 b4 = *(const ushort4*)(Bh2 + (size_t)i * 4);
        unsigned base = CMB + ((unsigned)(key >> 2)) * 392u +
                        (unsigned)q * 8u + ((unsigned)(key & 3)) * 2u;
        *(unsigned short*)(smem + base)           = bf1(m + b2f(b4.x));
        *(unsigned short*)(smem + base + 5096u)   = bf1(m + b2f(b4.y));
        *(unsigned short*)(smem + base + 10192u)  = bf1(m + b2f(b4.z));
        *(unsigned short*)(smem + base + 15288u)  = bf1(m + b2f(b4.w));
      }
    }
  }
  __syncthreads();

  // x fragment from LDS (lane = token l16), pack fp32->bf16 at read (R12 pattern)
  auto xfrag = [&](int tt, int ks) -> bf16x8 {
    int tok = 16 * tt + l16;
    unsigned col = (unsigned)(128 * ks + 32 * lg);
    unsigned off = (unsigned)tok * 512u + (col ^ (((unsigned)tok & 15u) << 5));
    float4 v0 = *(const float4*)(smem + off);
    float4 v1 = *(const float4*)(smem + off + 16);
    union { u32x4 u; bf16x8 h; } pk;
    pk.u.x = pk2(v0.x, v0.y); pk.u.y = pk2(v0.z, v0.w);
    pk.u.z = pk2(v1.x, v1.y); pk.u.w = pk2(v1.z, v1.w);
    return pk.h;
  };

  // coalesced W fragment: k-chunk kc = 4ks+lg, rows n..n+15 consecutive
  auto wfrag = [&](const unsigned short* base, int N, int kc, int n) -> bf16x8 {
    return *(const bf16x8*)(base + ((size_t)kc * N + n) * 8);
  };

  // ============ GEMM1 pass A: Q^T,K^T tiles = mfma(W^T-frag, x-frag) ============
  f32x4 qt_acc[2][4], kt_acc[2][4];
#pragma unroll
  for (int dt = 0; dt < 2; ++dt) {
    f32x4 qb, kb;
#pragma unroll
    for (int i = 0; i < 4; ++i) {
      qb[i] = bsc[32 * w + 16 * dt + 4 * lg + i];
      kb[i] = bsc[128 + 32 * w + 16 * dt + 4 * lg + i];
    }
#pragma unroll
    for (int tt = 0; tt < 4; ++tt) { qt_acc[dt][tt] = qb; kt_acc[dt][tt] = kb; }
  }
#pragma unroll
  for (int ks = 0; ks < 4; ++ks) {
    int kc = 4 * ks + lg;
    bf16x8 xf[4];
#pragma unroll
    for (int tt = 0; tt < 4; ++tt) xf[tt] = xfrag(tt, ks);
#pragma unroll
    for (int dt = 0; dt < 2; ++dt) {
      bf16x8 wq = wfrag(qkvP, 384, kc, 32 * w + 16 * dt + l16);
      bf16x8 wk = wfrag(qkvP, 384, kc, 128 + 32 * w + 16 * dt + l16);
#pragma unroll
      for (int tt = 0; tt < 4; ++tt) {
        qt_acc[dt][tt] = MFMA_K32(wq, xf[tt], qt_acc[dt][tt]);
        kt_acc[dt][tt] = MFMA_K32(wk, xf[tt], kt_acc[dt][tt]);
      }
    }
  }
  bf16x4 qf[4][2], kf[4][2];
#pragma unroll
  for (int tt = 0; tt < 4; ++tt)
#pragma unroll
    for (int dt = 0; dt < 2; ++dt) {
      qf[tt][dt] = pack4(qt_acc[dt][tt][0], qt_acc[dt][tt][1], qt_acc[dt][tt][2], qt_acc[dt][tt][3]);
      kf[tt][dt] = pack4(kt_acc[dt][tt][0], kt_acc[dt][tt][1], kt_acc[dt][tt][2], kt_acc[dt][tt][3]);
    }

  // ============ GEMM1 pass B: V tiles = mfma(x-frag, Wv^T-frag) ============
  f32x4 v_acc[4][2];
  {
    float vb0 = bsc[256 + 32 * w + l16];
    float vb1 = bsc[256 + 32 * w + 16 + l16];
#pragma unroll
    for (int tt = 0; tt < 4; ++tt) {
      v_acc[tt][0] = (f32x4){vb0, vb0, vb0, vb0};
      v_acc[tt][1] = (f32x4){vb1, vb1, vb1, vb1};
    }
  }
#pragma unroll
  for (int ks = 0; ks < 4; ++ks) {
    int kc = 4 * ks + lg;
    bf16x8 xf[4];
#pragma unroll
    for (int tt = 0; tt < 4; ++tt) xf[tt] = xfrag(tt, ks);   // LDS re-read, cheap
#pragma unroll
    for (int dt = 0; dt < 2; ++dt) {
      bf16x8 wv = wfrag(qkvP, 384, kc, 256 + 32 * w + 16 * dt + l16);
#pragma unroll
      for (int tt = 0; tt < 4; ++tt) v_acc[tt][dt] = MFMA_K32(xf[tt], wv, v_acc[tt][dt]);
    }
  }
  bf16x4 vf[2][4];
#pragma unroll
  for (int dt = 0; dt < 2; ++dt)
#pragma unroll
    for (int tt = 0; tt < 4; ++tt)
      vf[dt][tt] = pack4(v_acc[tt][dt][0], v_acc[tt][dt][1], v_acc[tt][dt][2], v_acc[tt][dt][3]);

  __syncthreads();   // all waves done reading xs; first 16KB becomes `mid`

  // ============ QK^T (K=16): S^T[key][q] tiles, lane = q, regs = key ============
  f32x4 s_acc[4][4];  // [kt][qt]
#pragma unroll
  for (int kt = 0; kt < 4; ++kt)
#pragma unroll
    for (int qt = 0; qt < 4; ++qt) s_acc[kt][qt] = (f32x4){0.f, 0.f, 0.f, 0.f};
#pragma unroll
  for (int kt = 0; kt < 4; ++kt)
#pragma unroll
    for (int qt = 0; qt < 4; ++qt) {
      s_acc[kt][qt] = MFMA_K16(kf[kt][0], qf[qt][0], s_acc[kt][qt]);
      s_acc[kt][qt] = MFMA_K16(kf[kt][1], qf[qt][1], s_acc[kt][qt]);
    }

  // ====== combined bias+mask: one ushort4 LDS read per (qt,kt) + no-max softmax ======
  const unsigned cmb_base = CMB + (unsigned)w * 5096u;
  float rs_[4];
#pragma unroll
  for (int qt = 0; qt < 4; ++qt) {
    int q = 16 * qt + l16;
    bool qok = q < 49;
    unsigned qoff = (unsigned)(q > 48 ? 48 : q) * 8u;
    float sum = 0.f;
#pragma unroll
    for (int kt = 0; kt < 4; ++kt) {
      int k4 = 4 * kt + lg;
      unsigned k4off = (unsigned)(k4 > 12 ? 12 : k4) * 392u;
      ushort4 mu = *(const ushort4*)(smem + cmb_base + k4off + qoff);
      float ba[4] = {b2f(mu.x), b2f(mu.y), b2f(mu.z), b2f(mu.w)};
#pragma unroll
      for (int i = 0; i < 4; ++i) {
        int key = 16 * kt + 4 * lg + i;
        float v = s_acc[kt][qt][i];
        v = (qok && key < 49) ? (v + ba[i]) : -30000.0f;
        float e = __expf(v - 8.0f);
        s_acc[kt][qt][i] = e;
        sum += e;
      }
    }
    sum += __shfl_xor(sum, 16);
    sum += __shfl_xor(sum, 32);
    rs_[qt] = 1.0f / (sum + 1e-30f);   // padded rows: sum==0 -> rs finite
  }

  // ============ P frags in-register; PV (K=16): O^T[d][q], lane = q ============
  bf16x4 pf[4][4];  // [qt][kt]
#pragma unroll
  for (int qt = 0; qt < 4; ++qt)
#pragma unroll
    for (int kt = 0; kt < 4; ++kt)
      pf[qt][kt] = pack4(s_acc[kt][qt][0], s_acc[kt][qt][1], s_acc[kt][qt][2], s_acc[kt][qt][3]);

  f32x4 o_acc[2][4];  // [dt][qt]: lane = q, regs = d = 4lg+i
#pragma unroll
  for (int dt = 0; dt < 2; ++dt)
#pragma unroll
    for (int qt = 0; qt < 4; ++qt) o_acc[dt][qt] = (f32x4){0.f, 0.f, 0.f, 0.f};
#pragma unroll
  for (int kt = 0; kt < 4; ++kt)
#pragma unroll
    for (int dt = 0; dt < 2; ++dt)
#pragma unroll
      for (int qt = 0; qt < 4; ++qt)
        o_acc[dt][qt] = MFMA_K16(vf[dt][kt], pf[qt][kt], o_acc[dt][qt]);

  // ============ normalize + write mid[q][32w+16dt+4lg..+3] (uint2) ============
#pragma unroll
  for (int qt = 0; qt < 4; ++qt) {
    int q = 16 * qt + l16;
    float r = rs_[qt];
    unsigned rowb = (unsigned)q * 256u, sw = ((unsigned)q & 15u) << 4;
#pragma unroll
    for (int dt = 0; dt < 2; ++dt) {
      unsigned u0 = pk2(o_acc[dt][qt][0] * r, o_acc[dt][qt][1] * r);
      unsigned u1 = pk2(o_acc[dt][qt][2] * r, o_acc[dt][qt][3] * r);
      unsigned L = (unsigned)(64 * w + 32 * dt + 8 * lg);
      *(uint2*)(smem + rowb + (L ^ sw)) = make_uint2(u0, u1);
    }
  }
  __syncthreads();

  // ============ GEMM2 (K=32): out = mid @ projW + b; wave w: cols 32w..32w+31 ============
  f32x4 c2[2][4];
#pragma unroll
  for (int nt = 0; nt < 2; ++nt) {
    float pbv = proj_b[32 * w + 16 * nt + l16];
#pragma unroll
    for (int mt = 0; mt < 4; ++mt) c2[nt][mt] = (f32x4){pbv, pbv, pbv, pbv};
  }
#pragma unroll
  for (int ks = 0; ks < 4; ++ks) {
    int kc = 4 * ks + lg;
    bf16x8 a2[4];
#pragma unroll
    for (int mt = 0; mt < 4; ++mt) {
      int tok = 16 * mt + l16;
      unsigned byte = (unsigned)tok * 256u +
                      (((unsigned)(64 * ks + 16 * lg)) ^ (((unsigned)tok & 15u) << 4));
      a2[mt] = *(const bf16x8*)(smem + byte);
    }
#pragma unroll
    for (int nt = 0; nt < 2; ++nt) {
      bf16x8 b2 = wfrag(projP, 128, kc, 32 * w + 16 * nt + l16);
#pragma unroll
      for (int mt = 0; mt < 4; ++mt) c2[nt][mt] = MFMA_K32(a2[mt], b2, c2[nt][mt]);
    }
  }
  float* ob = out + (size_t)b * 6272;
#pragma unroll
  for (int mt = 0; mt < 4; ++mt)
#pragma unroll
    for (int nt = 0; nt < 2; ++nt)
#pragma unroll
      for (int i = 0; i < 4; ++i) {
        int r = 16 * mt + 4 * lg + i;
        if (r < 49) ob[r * 128 + 32 * w + 16 * nt + l16] = c2[nt][mt][i];
      }
}

extern "C" void kernel_launch(void* const* d_in, const int* in_sizes, int n_in,
                              void* d_out, int out_size, void* d_ws, size_t ws_size,
                              hipStream_t stream) {
  const float* x          = (const float*)d_in[0];
  const float* mask       = (const float*)d_in[1];
  const float* qkv_w      = (const float*)d_in[2];
  const float* qkv_b      = (const float*)d_in[3];
  const float* proj_w     = (const float*)d_in[4];
  const float* proj_b     = (const float*)d_in[5];
  const float* bias_table = (const float*)d_in[6];
  const int*   rel_index  = (const int*)d_in[7];
  char* ws = (char*)d_ws;

  prep_kernel<<<296, 256, 0, stream>>>(qkv_w, qkv_b, proj_w, bias_table, rel_index, ws);
  win_attn_kernel<<<4096, 256, 0, stream>>>(x, mask, proj_b, ws, (float*)d_out);
}